// Round 1
// baseline (311.445 us; speedup 1.0000x reference)
//
#include <hip/hip_runtime.h>

// Reference short-circuit:
//   softmax over axis=1 of [S,1] == ones  ->  a = mask * e_t
//   c_t[h] = e_t * sum_{s in [w_start, w_end]} h_s[s][h]
// Window is <=129 rows; the S x H GEMV (h_s @ h_t) is dead code.

#define HIDDEN      1024
#define N_INTER     256
#define WINDOWF     64.0f
#define A_BLOCKS    64                      // kernel A: blocks; 4 rows each (1 per wave)
#define ROWS_PER_BLOCK (N_INTER / A_BLOCKS) // 4
#define C_COL_BLOCKS 4                      // 4 * 256 = 1024 columns
#define C_ROW_CHUNKS 8                      // window split into 8 row chunks

__global__ __launch_bounds__(256) void ka_mlp(
    const float* __restrict__ ht, const float* __restrict__ fc1w,
    const float* __restrict__ fc1b, const float* __restrict__ fc2w,
    float* __restrict__ partials, float* __restrict__ out)
{
    __shared__ float sh_ht[HIDDEN];
    __shared__ float sh_w[4];
    const int tid = threadIdx.x;
    const int b   = blockIdx.x;

    for (int k = tid; k < HIDDEN; k += 256) sh_ht[k] = ht[k];
    if (b == 0) {
        // zero output for kernel C's atomics (d_out is poisoned 0xAA)
        for (int k = tid; k < HIDDEN; k += 256) out[k] = 0.0f;
    }
    __syncthreads();

    const int wave = tid >> 6;
    const int lane = tid & 63;
    const int r    = b * ROWS_PER_BLOCK + wave;   // one fc1 row per wave
    const float* __restrict__ row = fc1w + (size_t)r * HIDDEN;

    float d = 0.0f;
    #pragma unroll
    for (int k = 0; k < HIDDEN / 64; ++k) {
        const int idx = lane + 64 * k;            // coalesced 256B per wave-iter
        d += sh_ht[idx] * row[idx];
    }
    #pragma unroll
    for (int off = 32; off > 0; off >>= 1) d += __shfl_down(d, off);

    if (lane == 0) sh_w[wave] = tanhf(d + fc1b[r]) * fc2w[r];
    __syncthreads();
    if (tid == 0) partials[b] = sh_w[0] + sh_w[1] + sh_w[2] + sh_w[3];
}

__global__ __launch_bounds__(256) void kc_window(
    const float* __restrict__ hs, const float* __restrict__ partials,
    const float* __restrict__ fc2b, float* __restrict__ out, int S)
{
    __shared__ float sh_sc[3];  // e_t, w_start, w_end
    if (threadIdx.x == 0) {
        // Deterministic re-sum of the 64 partials -> every block computes
        // bit-identical scalars (same FP order), so window bounds agree.
        float z = 0.0f;
        for (int i = 0; i < A_BLOCKS; ++i) z += partials[i];
        z += fc2b[0];
        const float sig = 1.0f / (1.0f + expf(-z));
        const float p_t = (float)S * sig;
        float wsf = ceilf(p_t - WINDOWF);  if (wsf < 0.0f) wsf = 0.0f;
        float wef = floorf(p_t + WINDOWF);
        const float smax = (float)(S - 1); if (wef > smax) wef = smax;
        // e_t uses S (faithful reference quirk); 2*STD_SQUARED = 2048
        const float e_t = expf(((float)S - p_t) * (1.0f / 2048.0f));
        sh_sc[0] = e_t; sh_sc[1] = wsf; sh_sc[2] = wef;
    }
    __syncthreads();

    const float e_t = sh_sc[0];
    const int wstart = (int)sh_sc[1];
    const int wend   = (int)sh_sc[2];
    if (wend < wstart) return;

    const int count = wend - wstart + 1;                       // <= 129
    const int chunk = (count + C_ROW_CHUNKS - 1) / C_ROW_CHUNKS;
    const int r0 = wstart + (int)blockIdx.y * chunk;
    if (r0 > wend) return;
    int r1 = r0 + chunk - 1; if (r1 > wend) r1 = wend;

    const int col = (int)blockIdx.x * 256 + (int)threadIdx.x;  // coalesced
    float acc = 0.0f;
    for (int r = r0; r <= r1; ++r)
        acc += hs[(size_t)r * HIDDEN + col];

    atomicAdd(&out[col], e_t * acc);
}

extern "C" void kernel_launch(void* const* d_in, const int* in_sizes, int n_in,
                              void* d_out, int out_size, void* d_ws, size_t ws_size,
                              hipStream_t stream) {
    const float* hs   = (const float*)d_in[0];  // [S, 1024]
    const float* ht   = (const float*)d_in[1];  // [1, 1024]
    const float* fc1w = (const float*)d_in[2];  // [256, 1024]
    const float* fc1b = (const float*)d_in[3];  // [256]
    const float* fc2w = (const float*)d_in[4];  // [1, 256]
    const float* fc2b = (const float*)d_in[5];  // [1]
    // d_in[6] is S on device; derive on host instead (in_sizes is host memory)
    const int S = in_sizes[0] / HIDDEN;

    float* out      = (float*)d_out;
    float* partials = (float*)d_ws;             // 64 floats

    ka_mlp<<<A_BLOCKS, 256, 0, stream>>>(ht, fc1w, fc1b, fc2w, partials, out);
    kc_window<<<dim3(C_COL_BLOCKS, C_ROW_CHUNKS), 256, 0, stream>>>(
        hs, partials, fc2b, out, S);
}